// Round 7
// baseline (281.693 us; speedup 1.0000x reference)
//
#include <hip/hip_runtime.h>
#include <hip/hip_bf16.h>
#include <stdint.h>

// ---------- types ----------
typedef __attribute__((ext_vector_type(8))) __bf16 bf16x8;
typedef __attribute__((ext_vector_type(4))) float f32x4;

__device__ __forceinline__ unsigned short f2b(float f) {
    return __builtin_bit_cast(unsigned short, __float2bfloat16(f));
}
__device__ __forceinline__ float b2f(unsigned int u) {   // low 16 bits = bf16
    return __builtin_bit_cast(float, u << 16);
}

// async global -> LDS, 16B per lane (wave-uniform base + lane*16 dest order)
__device__ __forceinline__ void gload_lds16(const void* g, void* l) {
    __builtin_amdgcn_global_load_lds(
        (__attribute__((address_space(1))) void*)(uintptr_t)g,
        (__attribute__((address_space(3))) void*)l,
        16, 0, 0);
}

#define MFMA16(a, b, c) __builtin_amdgcn_mfma_f32_16x16x32_bf16((a), (b), (c), 0, 0, 0)

// ---------- constants ----------
// B=8192, S=39, A=4, D_IN=43 (pad 64), F=1024, E=8, C=10

// ---------- prep: SA pack + mixture weights ----------
__global__ void k_prep_sa(const float* __restrict__ state, const float* __restrict__ action,
                          const int* __restrict__ c, const float* __restrict__ Wte,
                          unsigned short* __restrict__ SA, float* __restrict__ wmix, int B) {
    int b = blockIdx.x * 256 + threadIdx.x;
    if (b >= B) return;
    unsigned short* row = SA + (size_t)b * 64;
#pragma unroll
    for (int i = 0; i < 39; ++i) row[i] = f2b(state[(size_t)b * 39 + i]);
#pragma unroll
    for (int i = 0; i < 4; ++i) row[39 + i] = f2b(action[(size_t)b * 4 + i]);
#pragma unroll
    for (int i = 43; i < 64; ++i) row[i] = 0;
    int ctx = c[b];
#pragma unroll
    for (int e = 0; e < 8; ++e) wmix[(size_t)b * 8 + e] = Wte[e * 10 + ctx];
}

// ---------- prep: W0 [E,43,1024] f32 -> W0T [E,1024,64] bf16 ----------
__global__ void k_prep_w0t(const float* __restrict__ W0, unsigned short* __restrict__ W0T) {
    int idx = blockIdx.x * 256 + threadIdx.x;   // e*1024 + f
    int e = idx >> 10, f = idx & 1023;
    unsigned short* dst = W0T + (size_t)idx * 64;
#pragma unroll 1
    for (int k = 0; k < 43; ++k) dst[k] = f2b(W0[((size_t)e * 43 + k) * 1024 + f]);
#pragma unroll
    for (int k = 43; k < 64; ++k) dst[k] = 0;
}

// ---------- prep: W1 [E,1024,1024] f32 -> W1T [E,1024(n),1024(k)] bf16 ----------
__global__ void k_prep_w1t(const float* __restrict__ W1, unsigned short* __restrict__ W1T) {
    __shared__ float t[64][65];
    int k0 = blockIdx.x * 64, n0 = blockIdx.y * 64, e = blockIdx.z;
    int tid = threadIdx.x;
    int cl = tid & 63, rg = tid >> 6;
    const float* src = W1 + ((size_t)e * 1024 + k0) * 1024 + n0;
#pragma unroll
    for (int i = 0; i < 16; ++i) {
        int kr = rg * 16 + i;
        t[kr][cl] = src[(size_t)kr * 1024 + cl];
    }
    __syncthreads();
    int nl = tid >> 2, kg = tid & 3;
    unsigned short* dst = W1T + ((size_t)e * 1024 + n0 + nl) * 1024 + k0 + kg * 16;
#pragma unroll
    for (int j = 0; j < 16; ++j) dst[j] = f2b(t[kg * 16 + j][nl]);
}

// ---------- layer 0: H0[e] = relu(SA @ W0T[e]^T + b0[e]), bf16 out ----------
__global__ __launch_bounds__(256, 2)
void k_layer0(const unsigned short* __restrict__ SA,
              const unsigned short* __restrict__ W0T,
              const float* __restrict__ b0,
              unsigned short* __restrict__ H0,
              int Bc, int row0) {
    __shared__ unsigned short As[128 * 64];
    __shared__ unsigned short Bs[128 * 64];
    int bm = blockIdx.x, bn = blockIdx.y, e = blockIdx.z;
    int tid = threadIdx.x, lane = tid & 63;
    int wv = tid >> 6, wr = wv >> 1, wc = wv & 1;
    int l15 = lane & 15, kg = lane >> 4;

    const char* Ag = (const char*)(SA + (size_t)(row0 + bm * 128) * 64);
    const char* Bg = (const char*)(W0T + ((size_t)e * 1024 + bn * 128) * 64);
#pragma unroll
    for (int it = 0; it < 4; ++it) {
        int off = tid * 16 + it * 4096;
        gload_lds16(Ag + off, (char*)As + off);
        gload_lds16(Bg + off, (char*)Bs + off);
    }
    __syncthreads();

    f32x4 acc[4][4];
#pragma unroll
    for (int mi = 0; mi < 4; ++mi)
#pragma unroll
        for (int ni = 0; ni < 4; ++ni) acc[mi][ni] = (f32x4)0.0f;

#pragma unroll
    for (int ks = 0; ks < 2; ++ks) {
        bf16x8 af[4], bv[4];
#pragma unroll
        for (int mi = 0; mi < 4; ++mi)
            af[mi] = *(const bf16x8*)&As[(wr * 64 + mi * 16 + l15) * 64 + ks * 32 + kg * 8];
#pragma unroll
        for (int ni = 0; ni < 4; ++ni)
            bv[ni] = *(const bf16x8*)&Bs[(wc * 64 + ni * 16 + l15) * 64 + ks * 32 + kg * 8];
#pragma unroll
        for (int mi = 0; mi < 4; ++mi)
#pragma unroll
            for (int ni = 0; ni < 4; ++ni)
                acc[mi][ni] = MFMA16(af[mi], bv[ni], acc[mi][ni]);
    }

    float b0v[4];
#pragma unroll
    for (int ni = 0; ni < 4; ++ni)
        b0v[ni] = b0[e * 1024 + bn * 128 + wc * 64 + ni * 16 + l15];
#pragma unroll
    for (int mi = 0; mi < 4; ++mi)
#pragma unroll
        for (int ni = 0; ni < 4; ++ni)
#pragma unroll
            for (int j = 0; j < 4; ++j) {
                int rloc = bm * 128 + wr * 64 + mi * 16 + kg * 4 + j;
                int col = bn * 128 + wc * 64 + ni * 16 + l15;
                float h = fmaxf(acc[mi][ni][j] + b0v[ni], 0.0f);
                H0[((size_t)e * Bc + rloc) * 1024 + col] = f2b(h);
            }
}

// ---------- layer 1 + mixing: 256x256 tile, 8 waves of 128x64, expert-split ----------
// Each block handles 4 experts (group g) and writes a bf16 PARTIAL mixed
// (pre-final-relu; mix is linear across experts). Head combines the 2 partials.
// Per K-tile(BK=64): two sub-phases {12 ds_read || 4 gload -> lgkm(0) -> 32 MFMA},
// then one vmcnt(0)+s_barrier (t+1's 8 loads were issued this tile, ~2500cy lead).
// Wave tile 128x64 -> LDS-read bytes/FLOP = 0.0229, feeds the MFMA pipe (m201 geometry).
__global__ __launch_bounds__(512, 2)
void k_layer1_mix(const unsigned short* __restrict__ H0,   // [E,Bc,1024]
                  const unsigned short* __restrict__ W1T,  // [E,1024(n),1024(k)]
                  const float* __restrict__ b1,            // [E,1024]
                  const float* __restrict__ wmix,          // [B,8]
                  unsigned short* __restrict__ mixedP,     // [2][Bc,1024] bf16 partials
                  int Bc, int row0) {
    __shared__ unsigned short As[2][256 * 64];   // 2 x 32 KB
    __shared__ unsigned short Bs[2][256 * 64];   // 2 x 32 KB
    __shared__ float wmixLds[256 * 4];           // 4 KB (this block's 4 experts)
    __shared__ float b1Lds[4 * 256];             // 4 KB

    int nbm = Bc / 256;
    int P = nbm * 2;                 // (bm,g) pairs
    int wg = blockIdx.x;
    int bm, bn, g;
    if ((P & 7) == 0) {
        // XCD-coherent: assumes xcd = wg%8; the 4 bn-siblings of a (bm,g) pair
        // land on one XCD so the H0 panel flows through that L2 once.
        int c8 = wg & 7, j = wg >> 3;
        int p = c8 + 8 * (j >> 2);
        bn = j & 3;
        bm = p >> 1; g = p & 1;
    } else {
        bn = wg & 3; g = (wg >> 2) & 1; bm = wg >> 3;
    }

    int tid = threadIdx.x, lane = tid & 63;
    int wv = tid >> 6;
    int wr = wv >> 2, wc = wv & 3;               // 2M x 4N waves of 128x64
    int l15 = lane & 15, kg = lane >> 4;
    int kg16 = kg * 16;
    int xsw = (l15 & 7) << 4;

    // staging maps: 16B/lane; A and B each 32 KB = 4 issues of 8 KB
    int tid16 = tid * 16;
    int sSrc[4], sDst[4];
#pragma unroll
    for (int i = 0; i < 4; ++i) {
        int flat = tid16 + i * 8192;
        int row = flat >> 7, colb = flat & 127;
        sDst[i] = flat;
        sSrc[i] = row * 2048 + (colb ^ ((row & 7) << 4));   // inverse-swizzled source
    }

    const char* h0base = (const char*)H0 + (size_t)(bm * 256) * 2048;
    const char* w1base = (const char*)W1T + (size_t)(bn * 256) * 2048;
    size_t eAstride = (size_t)Bc * 2048;

    // fragment read offsets (swizzled; row&7 == l15&7)
    int aOff[8], bOff[4];
#pragma unroll
    for (int m = 0; m < 8; ++m) aOff[m] = (wr * 128 + m * 16 + l15) * 128;
#pragma unroll
    for (int n = 0; n < 4; ++n) bOff[n] = (wc * 64 + n * 16 + l15) * 128;

    // preload wmix (4 experts of group g) + b1 into LDS
    for (int idx = tid; idx < 1024; idx += 512) {
        int r = idx >> 2, el = idx & 3;
        wmixLds[idx] = wmix[(size_t)(row0 + bm * 256 + r) * 8 + g * 4 + el];
    }
    for (int idx = tid; idx < 1024; idx += 512)
        b1Lds[idx] = b1[(g * 4 + (idx >> 8)) * 1024 + bn * 256 + (idx & 255)];

    f32x4 acc[8], acc2[8];        // acc[m] for n-pairs: use [8][4]? keep [8][4] explicit
    // full accumulators: 8m x 4n quarters
    f32x4 A0[8][4];
    float mix[8][4][4];
#pragma unroll
    for (int m = 0; m < 8; ++m)
#pragma unroll
        for (int n = 0; n < 4; ++n) {
            A0[m][n] = (f32x4)0.0f;
#pragma unroll
            for (int j = 0; j < 4; ++j) mix[m][n][j] = 0.0f;
        }
    (void)acc; (void)acc2;

    const int NT = 64;   // 4 experts * 16 K-tiles (BK=64)

    auto STAGE_G = [&](int tt, int half) {   // half 0: issues {A0,A1,B0,B1}; half 1: {A2,A3,B2,B3}
        int el = tt >> 4;
        int k0b = (tt & 15) << 7;
        const char* Ab = h0base + (size_t)(g * 4 + el) * eAstride + k0b;
        const char* Bb = w1base + (size_t)(g * 4 + el) * (1024 * 2048) + k0b;
        char* Ad = (char*)As[tt & 1];
        char* Bd = (char*)Bs[tt & 1];
        int i0 = half * 2;
        gload_lds16(Ab + sSrc[i0], Ad + sDst[i0]);
        gload_lds16(Ab + sSrc[i0 + 1], Ad + sDst[i0 + 1]);
        gload_lds16(Bb + sSrc[i0], Bd + sDst[i0]);
        gload_lds16(Bb + sSrc[i0 + 1], Bd + sDst[i0 + 1]);
    };

    // prologue: stage tile 0 fully, drain, barrier
    STAGE_G(0, 0);
    STAGE_G(0, 1);
    __syncthreads();   // drains vmcnt+lgkm for all waves

#pragma unroll 1
    for (int t = 0; t < NT; ++t) {
        const char* Ab = (const char*)As[t & 1];
        const char* Bb = (const char*)Bs[t & 1];

        // ---- sub-phase k-step 0 ----
        {
            int kb = kg16 ^ xsw;
            bf16x8 af[8], bf[4];
#pragma unroll
            for (int m = 0; m < 8; ++m) af[m] = *(const bf16x8*)(Ab + aOff[m] + kb);
#pragma unroll
            for (int n = 0; n < 4; ++n) bf[n] = *(const bf16x8*)(Bb + bOff[n] + kb);
            if (t + 1 < NT) STAGE_G(t + 1, 0);
            asm volatile("s_waitcnt lgkmcnt(0)" ::: "memory");
            __builtin_amdgcn_sched_barrier(0);
            __builtin_amdgcn_s_setprio(1);
#pragma unroll
            for (int m = 0; m < 8; ++m)
#pragma unroll
                for (int n = 0; n < 4; ++n)
                    A0[m][n] = MFMA16(af[m], bf[n], A0[m][n]);
            __builtin_amdgcn_s_setprio(0);
            __builtin_amdgcn_sched_barrier(0);
        }
        // ---- sub-phase k-step 1 ----
        {
            int kb = (64 + kg16) ^ xsw;
            bf16x8 af[8], bf[4];
#pragma unroll
            for (int m = 0; m < 8; ++m) af[m] = *(const bf16x8*)(Ab + aOff[m] + kb);
#pragma unroll
            for (int n = 0; n < 4; ++n) bf[n] = *(const bf16x8*)(Bb + bOff[n] + kb);
            if (t + 1 < NT) STAGE_G(t + 1, 1);
            asm volatile("s_waitcnt lgkmcnt(0)" ::: "memory");
            __builtin_amdgcn_sched_barrier(0);
            __builtin_amdgcn_s_setprio(1);
#pragma unroll
            for (int m = 0; m < 8; ++m)
#pragma unroll
                for (int n = 0; n < 4; ++n)
                    A0[m][n] = MFMA16(af[m], bf[n], A0[m][n]);
            __builtin_amdgcn_s_setprio(0);
            __builtin_amdgcn_sched_barrier(0);
        }
        // tile boundary: t+1's 8 loads must have landed; all lgkm drained above,
        // so after this barrier buf[(t+1)&1] is safe to read and buf[t&1] to overwrite.
        asm volatile("s_waitcnt vmcnt(0)\n\ts_barrier" ::: "memory");

        if ((t & 15) == 15) {
            // per-expert epilogue: bias + relu + weighted accumulate (LDS-const only)
            int el = t >> 4;
            float b1v[4];
#pragma unroll
            for (int n = 0; n < 4; ++n)
                b1v[n] = b1Lds[el * 256 + wc * 64 + n * 16 + l15];
#pragma unroll
            for (int m = 0; m < 8; ++m)
#pragma unroll
                for (int j = 0; j < 4; ++j) {
                    int lrow = wr * 128 + m * 16 + kg * 4 + j;
                    float w = wmixLds[lrow * 4 + el];
#pragma unroll
                    for (int n = 0; n < 4; ++n) {
                        float h = fmaxf(A0[m][n][j] + b1v[n], 0.0f);
                        mix[m][n][j] += w * h;
                        A0[m][n][j] = 0.0f;
                    }
                }
        }
    }

    // store bf16 partial (no final relu here — head combines partials then relus)
    unsigned short* outp = mixedP + (size_t)g * Bc * 1024;
#pragma unroll
    for (int m = 0; m < 8; ++m)
#pragma unroll
        for (int n = 0; n < 4; ++n)
#pragma unroll
            for (int j = 0; j < 4; ++j) {
                int lrow = wr * 128 + m * 16 + kg * 4 + j;
                int col = bn * 256 + wc * 64 + n * 16 + l15;
                outp[(size_t)(bm * 256 + lrow) * 1024 + col] = f2b(mix[m][n][j]);
            }
}

// ---------- head: q[b] = relu(mix0[b]+mix1[b]) . Wh[c[b]] + bh[c[b]] ----------
__global__ void k_head(const unsigned short* __restrict__ mixedP,  // [2][Bc,1024] bf16
                       const float* __restrict__ Wh, const float* __restrict__ bh,
                       const int* __restrict__ c, float* __restrict__ q,
                       int Bc, int row0) {
    int row = blockIdx.x * 4 + (threadIdx.x >> 6);
    int lane = threadIdx.x & 63;
    if (row >= Bc) return;
    int grow = row0 + row;
    int ctx = c[grow];
    const unsigned short* pa = mixedP + (size_t)row * 1024 + lane * 16;
    const unsigned short* pb = mixedP + (size_t)Bc * 1024 + (size_t)row * 1024 + lane * 16;
    const float* wv = Wh + (size_t)ctx * 1024 + lane * 16;
    float s = 0.0f;
#pragma unroll
    for (int ch = 0; ch < 2; ++ch) {
        uint4 ua = *(const uint4*)(pa + ch * 8);
        uint4 ub = *(const uint4*)(pb + ch * 8);
        const float* w8 = wv + ch * 8;
        unsigned int au[4] = {ua.x, ua.y, ua.z, ua.w};
        unsigned int bu[4] = {ub.x, ub.y, ub.z, ub.w};
#pragma unroll
        for (int i = 0; i < 4; ++i) {
            float a0 = b2f(au[i] & 0xffffu), a1 = b2f(au[i] >> 16);
            float c0 = b2f(bu[i] & 0xffffu), c1 = b2f(bu[i] >> 16);
            s += fmaxf(a0 + c0, 0.0f) * w8[i * 2];
            s += fmaxf(a1 + c1, 0.0f) * w8[i * 2 + 1];
        }
    }
#pragma unroll
    for (int off = 32; off > 0; off >>= 1) s += __shfl_down(s, off);
    if (lane == 0) q[grow] = s + bh[ctx];
}

// ---------- host ----------
extern "C" void kernel_launch(void* const* d_in, const int* in_sizes, int n_in,
                              void* d_out, int out_size, void* d_ws, size_t ws_size,
                              hipStream_t stream) {
    const float* state  = (const float*)d_in[0];
    const float* action = (const float*)d_in[1];
    const int*   c      = (const int*)d_in[2];
    const float* W0     = (const float*)d_in[3];
    const float* b0     = (const float*)d_in[4];
    const float* W1     = (const float*)d_in[5];
    const float* b1     = (const float*)d_in[6];
    const float* Wte    = (const float*)d_in[7];
    const float* Wh     = (const float*)d_in[8];
    const float* bh     = (const float*)d_in[9];
    float* q = (float*)d_out;
    int B = in_sizes[2];

    // workspace layout
    char* p = (char*)d_ws;
    unsigned short* W1T = (unsigned short*)p; p += (size_t)8 * 1024 * 1024 * 2;  // 16 MB
    unsigned short* W0T = (unsigned short*)p; p += (size_t)8 * 1024 * 64 * 2;    // 1 MB
    unsigned short* SA  = (unsigned short*)p; p += (size_t)B * 64 * 2;
    float* wmix         = (float*)p;          p += (size_t)B * 8 * 4;
    size_t fixed = (size_t)(p - (char*)d_ws);

    // per-row chunk cost: H0 8*2KB + mixed partials 2*2KB = 20.5 KB
    int Bc = B;
    while (Bc > 256 && fixed + (size_t)Bc * (8 * 1024 * 2 + 2 * 1024 * 2) > ws_size) Bc >>= 1;

    unsigned short* H0     = (unsigned short*)p; p += (size_t)8 * Bc * 1024 * 2;
    unsigned short* mixedP = (unsigned short*)p;   // [2][Bc][1024] bf16

    k_prep_sa<<<(B + 255) / 256, 256, 0, stream>>>(state, action, c, Wte, SA, wmix, B);
    k_prep_w0t<<<(8 * 1024) / 256, 256, 0, stream>>>(W0, W0T);
    k_prep_w1t<<<dim3(16, 16, 8), 256, 0, stream>>>(W1, W1T);

    for (int row0 = 0; row0 < B; row0 += Bc) {
        k_layer0<<<dim3(Bc / 128, 8, 8), 256, 0, stream>>>(SA, W0T, b0, H0, Bc, row0);
        k_layer1_mix<<<(Bc / 256) * 8, 512, 0, stream>>>(H0, W1T, b1, wmix, mixedP, Bc, row0);
        k_head<<<(Bc + 3) / 4, 256, 0, stream>>>(mixedP, Wh, bh, c, q, Bc, row0);
    }
}

// Round 9
// 251.620 us; speedup vs baseline: 1.1195x; 1.1195x over previous
//
#include <hip/hip_runtime.h>
#include <hip/hip_bf16.h>
#include <stdint.h>

// ---------- types ----------
typedef __attribute__((ext_vector_type(8))) __bf16 bf16x8;
typedef __attribute__((ext_vector_type(4))) float f32x4;

__device__ __forceinline__ unsigned short f2b(float f) {
    return __builtin_bit_cast(unsigned short, __float2bfloat16(f));
}
__device__ __forceinline__ float b2f(unsigned int u) {   // low 16 bits = bf16
    return __builtin_bit_cast(float, u << 16);
}

// async global -> LDS, 16B per lane (wave-uniform base + lane*16 dest order)
__device__ __forceinline__ void gload_lds16(const void* g, void* l) {
    __builtin_amdgcn_global_load_lds(
        (__attribute__((address_space(1))) void*)(uintptr_t)g,
        (__attribute__((address_space(3))) void*)l,
        16, 0, 0);
}

#define MFMA16(a, b, c) __builtin_amdgcn_mfma_f32_16x16x32_bf16((a), (b), (c), 0, 0, 0)

// ---------- constants ----------
// B=8192, S=39, A=4, D_IN=43 (pad 64), F=1024, E=8, C=10

// ---------- prep: SA pack + mixture weights ----------
__global__ void k_prep_sa(const float* __restrict__ state, const float* __restrict__ action,
                          const int* __restrict__ c, const float* __restrict__ Wte,
                          unsigned short* __restrict__ SA, float* __restrict__ wmix, int B) {
    int b = blockIdx.x * 256 + threadIdx.x;
    if (b >= B) return;
    unsigned short* row = SA + (size_t)b * 64;
#pragma unroll
    for (int i = 0; i < 39; ++i) row[i] = f2b(state[(size_t)b * 39 + i]);
#pragma unroll
    for (int i = 0; i < 4; ++i) row[39 + i] = f2b(action[(size_t)b * 4 + i]);
#pragma unroll
    for (int i = 43; i < 64; ++i) row[i] = 0;
    int ctx = c[b];
#pragma unroll
    for (int e = 0; e < 8; ++e) wmix[(size_t)b * 8 + e] = Wte[e * 10 + ctx];
}

// ---------- prep: W0 [E,43,1024] f32 -> W0T [E,1024,64] bf16 ----------
__global__ void k_prep_w0t(const float* __restrict__ W0, unsigned short* __restrict__ W0T) {
    int idx = blockIdx.x * 256 + threadIdx.x;   // e*1024 + f
    int e = idx >> 10, f = idx & 1023;
    unsigned short* dst = W0T + (size_t)idx * 64;
#pragma unroll 1
    for (int k = 0; k < 43; ++k) dst[k] = f2b(W0[((size_t)e * 43 + k) * 1024 + f]);
#pragma unroll
    for (int k = 43; k < 64; ++k) dst[k] = 0;
}

// ---------- prep: W1 [E,1024,1024] f32 -> W1T [E,1024(n),1024(k)] bf16 ----------
__global__ void k_prep_w1t(const float* __restrict__ W1, unsigned short* __restrict__ W1T) {
    __shared__ float t[64][65];
    int k0 = blockIdx.x * 64, n0 = blockIdx.y * 64, e = blockIdx.z;
    int tid = threadIdx.x;
    int cl = tid & 63, rg = tid >> 6;
    const float* src = W1 + ((size_t)e * 1024 + k0) * 1024 + n0;
#pragma unroll
    for (int i = 0; i < 16; ++i) {
        int kr = rg * 16 + i;
        t[kr][cl] = src[(size_t)kr * 1024 + cl];
    }
    __syncthreads();
    int nl = tid >> 2, kg = tid & 3;
    unsigned short* dst = W1T + ((size_t)e * 1024 + n0 + nl) * 1024 + k0 + kg * 16;
#pragma unroll
    for (int j = 0; j < 16; ++j) dst[j] = f2b(t[kg * 16 + j][nl]);
}

// ---------- layer 0: H0[e] = relu(SA @ W0T[e]^T + b0[e]), bf16 out ----------
__global__ __launch_bounds__(256, 2)
void k_layer0(const unsigned short* __restrict__ SA,
              const unsigned short* __restrict__ W0T,
              const float* __restrict__ b0,
              unsigned short* __restrict__ H0,
              int Bc, int row0) {
    __shared__ unsigned short As[128 * 64];
    __shared__ unsigned short Bs[128 * 64];
    int bm = blockIdx.x, bn = blockIdx.y, e = blockIdx.z;
    int tid = threadIdx.x, lane = tid & 63;
    int wv = tid >> 6, wr = wv >> 1, wc = wv & 1;
    int l15 = lane & 15, kg = lane >> 4;

    const char* Ag = (const char*)(SA + (size_t)(row0 + bm * 128) * 64);
    const char* Bg = (const char*)(W0T + ((size_t)e * 1024 + bn * 128) * 64);
#pragma unroll
    for (int it = 0; it < 4; ++it) {
        int off = tid * 16 + it * 4096;
        gload_lds16(Ag + off, (char*)As + off);
        gload_lds16(Bg + off, (char*)Bs + off);
    }
    __syncthreads();

    f32x4 acc[4][4];
#pragma unroll
    for (int mi = 0; mi < 4; ++mi)
#pragma unroll
        for (int ni = 0; ni < 4; ++ni) acc[mi][ni] = (f32x4)0.0f;

#pragma unroll
    for (int ks = 0; ks < 2; ++ks) {
        bf16x8 af[4], bv[4];
#pragma unroll
        for (int mi = 0; mi < 4; ++mi)
            af[mi] = *(const bf16x8*)&As[(wr * 64 + mi * 16 + l15) * 64 + ks * 32 + kg * 8];
#pragma unroll
        for (int ni = 0; ni < 4; ++ni)
            bv[ni] = *(const bf16x8*)&Bs[(wc * 64 + ni * 16 + l15) * 64 + ks * 32 + kg * 8];
#pragma unroll
        for (int mi = 0; mi < 4; ++mi)
#pragma unroll
            for (int ni = 0; ni < 4; ++ni)
                acc[mi][ni] = MFMA16(af[mi], bv[ni], acc[mi][ni]);
    }

    float b0v[4];
#pragma unroll
    for (int ni = 0; ni < 4; ++ni)
        b0v[ni] = b0[e * 1024 + bn * 128 + wc * 64 + ni * 16 + l15];
#pragma unroll
    for (int mi = 0; mi < 4; ++mi)
#pragma unroll
        for (int ni = 0; ni < 4; ++ni)
#pragma unroll
            for (int j = 0; j < 4; ++j) {
                int rloc = bm * 128 + wr * 64 + mi * 16 + kg * 4 + j;
                int col = bn * 128 + wc * 64 + ni * 16 + l15;
                float h = fmaxf(acc[mi][ni][j] + b0v[ni], 0.0f);
                H0[((size_t)e * Bc + rloc) * 1024 + col] = f2b(h);
            }
}

// ---------- pass A: H1[e] = relu(H0[e] @ W1T[e]^T + b1[e]), fragment-layout bf16 out ----------
// m201 template: 256x256 block, 512 thr = 8 waves (2M x 4N), per-wave 128x64, BK=64,
// LDS 128 KB. Per K-tile 4 phases: {ds_read subtile [+stage] -> barrier -> lgkm(0)
// -> setprio(1) 16 MFMA setprio(0) -> barrier}.
// STAGING DISCIPLINE (fixes R8 race): a write into buf[t] is only ISSUED after the
// barrier certifying its region's last read. B-halves of buf[t] are fully read by
// end of P1 -> stage B(t+2) at P2; A-halves fully read by end of P2 -> stage A(t+2)
// at P3. Tile t+1 (opposite buffer) was staged during iteration t-1. FIFO at the
// trailing gate: [B(t+1)4 A(t+1)4 B(t+2)4 A(t+2)4] -> vmcnt(8) certifies t+1 landed;
// never drains to 0 mid-loop; ~6 phases of load lead.
__global__ __launch_bounds__(512, 2)
void k_gemm_h1(const unsigned short* __restrict__ H0,   // [E,Bc,1024]
               const unsigned short* __restrict__ W1T,  // [E,1024(n),1024(k)]
               const float* __restrict__ b1,            // [E,1024]
               uint2* __restrict__ H1F,                 // fragment layout, see store
               int Bc, int nbm) {
    __shared__ unsigned short SH[65536];   // 128 KB: A bytes [0,65536), B [65536,131072)

    // XCD-coherent decode (xcd = wg%8): the 4 bn-siblings of one (e,bm) pair —
    // which share the H0 A-panel — land on one XCD's L2.
    int wg = blockIdx.x;
    int c8 = wg & 7, r = wg >> 3;
    int bn = r & 3, pg = r >> 2;
    int pair = c8 + 8 * pg;                // pair = e*nbm + bm, npair = 8*nbm (%8==0)
    int e = pair / nbm, bm = pair - e * nbm;

    int tid = threadIdx.x, lane = tid & 63;
    int wv = tid >> 6;
    int wr = wv >> 2, wc = wv & 3;         // 2M x 4N wave grid
    int l15 = lane & 15, kg = lane >> 4;
    int k0s = (kg * 16) ^ ((l15 & 7) << 4);
    int k1s = (64 + kg * 16) ^ ((l15 & 7) << 4);

    // staging per-thread offsets: half-tile = 16 KB = 2 issues x 512thr x 16B
    int flat = tid * 16;
    int srow = flat >> 7;                          // 0..63
    int scol = (flat & 127) ^ ((srow & 7) << 4);   // inverse-swizzled source col

    const char* h0e = (const char*)H0 + ((size_t)e * Bc + (size_t)bm * 256) * 2048;
    const char* w1e = (const char*)W1T + ((size_t)e * 1024 + (size_t)bn * 256) * 2048;
    char* Asb = (char*)SH;
    char* Bsb = (char*)SH + 65536;

    // fragment read offsets (rows local to the wave's half; row&7 == l15&7)
    int aRow[8], bRow[4];
#pragma unroll
    for (int m = 0; m < 8; ++m) aRow[m] = (((m >> 2) * 64) + (m & 3) * 16 + l15) * 128;
#pragma unroll
    for (int n = 0; n < 4; ++n) bRow[n] = ((wc & 1) * 64 + n * 16 + l15) * 128;

    // bias: load + force retirement BEFORE the pipeline (keeps vmcnt FIFO clean)
    float b1v[4];
#pragma unroll
    for (int n = 0; n < 4; ++n)
        b1v[n] = b1[e * 1024 + bn * 256 + wc * 64 + n * 16 + l15];
    asm volatile("s_waitcnt vmcnt(0)" ::: "memory");

    // stage both halves of one operand's K-tile tt (4 loads each)
    auto STAGE_B2 = [&](int tt) {
        int k0b = tt << 7;
        char* dstb = Bsb + (tt & 1) * 32768;
        const char* s0 = w1e + k0b;                          // rows 0..127 (half 0)
        gload_lds16(s0 + (size_t)srow * 2048 + scol, dstb + flat);
        gload_lds16(s0 + (size_t)(srow + 64) * 2048 + scol, dstb + flat + 8192);
        const char* s1 = w1e + (size_t)128 * 2048 + k0b;     // rows 128..255 (half 1)
        gload_lds16(s1 + (size_t)srow * 2048 + scol, dstb + 16384 + flat);
        gload_lds16(s1 + (size_t)(srow + 64) * 2048 + scol, dstb + 16384 + flat + 8192);
    };
    auto STAGE_A2 = [&](int tt) {
        int k0b = tt << 7;
        char* dsta = Asb + (tt & 1) * 32768;
        const char* s0 = h0e + k0b;
        gload_lds16(s0 + (size_t)srow * 2048 + scol, dsta + flat);
        gload_lds16(s0 + (size_t)(srow + 64) * 2048 + scol, dsta + flat + 8192);
        const char* s1 = h0e + (size_t)128 * 2048 + k0b;
        gload_lds16(s1 + (size_t)srow * 2048 + scol, dsta + 16384 + flat);
        gload_lds16(s1 + (size_t)(srow + 64) * 2048 + scol, dsta + 16384 + flat + 8192);
    };

    const int NT = 16;   // K = 1024 / BK 64

    // prologue: stage tiles 0 and 1 (FIFO [B0 A0 B1 A1]); vmcnt(8) drains tile 0
    STAGE_B2(0); STAGE_A2(0);
    STAGE_B2(1); STAGE_A2(1);
    asm volatile("s_waitcnt vmcnt(8)" ::: "memory");
    __builtin_amdgcn_s_barrier();

    f32x4 acc[8][4];
#pragma unroll
    for (int m = 0; m < 8; ++m)
#pragma unroll
        for (int n = 0; n < 4; ++n) acc[m][n] = (f32x4)0.0f;

#pragma unroll 1
    for (int t = 0; t < NT; ++t) {
        int buf = t & 1;
        const char* Ab = Asb + (buf * 2 + wr) * 16384;          // wave's A half
        const char* Bb = Bsb + (buf * 2 + (wc >> 1)) * 16384;   // wave's B half

        bf16x8 af[4][2], bf0[2][2], bf1[2][2];

        // ===== P0: read af(m0) + bf(n0); MFMA m0 x n0 =====
#pragma unroll
        for (int mi = 0; mi < 4; ++mi) {
            af[mi][0] = *(const bf16x8*)(Ab + aRow[mi] + k0s);
            af[mi][1] = *(const bf16x8*)(Ab + aRow[mi] + k1s);
        }
#pragma unroll
        for (int ni = 0; ni < 2; ++ni) {
            bf0[ni][0] = *(const bf16x8*)(Bb + bRow[ni] + k0s);
            bf0[ni][1] = *(const bf16x8*)(Bb + bRow[ni] + k1s);
        }
        __builtin_amdgcn_s_barrier();
        asm volatile("s_waitcnt lgkmcnt(0)" ::: "memory");
        __builtin_amdgcn_sched_barrier(0);
        __builtin_amdgcn_s_setprio(1);
#pragma unroll
        for (int k = 0; k < 2; ++k)
#pragma unroll
            for (int mi = 0; mi < 4; ++mi)
#pragma unroll
                for (int ni = 0; ni < 2; ++ni)
                    acc[mi][ni] = MFMA16(af[mi][k], bf0[ni][k], acc[mi][ni]);
        __builtin_amdgcn_s_setprio(0);
        __builtin_amdgcn_sched_barrier(0);
        __builtin_amdgcn_s_barrier();

        // ===== P1: read bf(n1); MFMA m0 x n1  (B-halves of buf fully read after this) =====
#pragma unroll
        for (int ni = 0; ni < 2; ++ni) {
            bf1[ni][0] = *(const bf16x8*)(Bb + bRow[2 + ni] + k0s);
            bf1[ni][1] = *(const bf16x8*)(Bb + bRow[2 + ni] + k1s);
        }
        __builtin_amdgcn_s_barrier();
        asm volatile("s_waitcnt lgkmcnt(0)" ::: "memory");
        __builtin_amdgcn_sched_barrier(0);
        __builtin_amdgcn_s_setprio(1);
#pragma unroll
        for (int k = 0; k < 2; ++k)
#pragma unroll
            for (int mi = 0; mi < 4; ++mi)
#pragma unroll
                for (int ni = 0; ni < 2; ++ni)
                    acc[mi][2 + ni] = MFMA16(af[mi][k], bf1[ni][k], acc[mi][2 + ni]);
        __builtin_amdgcn_s_setprio(0);
        __builtin_amdgcn_sched_barrier(0);
        __builtin_amdgcn_s_barrier();

        // ===== P2: read af(m1); stage B(t+2) (B regions of this buf are free);
        //           MFMA m1 x n1 =====
#pragma unroll
        for (int mi = 0; mi < 4; ++mi) {
            af[mi][0] = *(const bf16x8*)(Ab + aRow[4 + mi] + k0s);
            af[mi][1] = *(const bf16x8*)(Ab + aRow[4 + mi] + k1s);
        }
        if (t + 2 < NT) STAGE_B2(t + 2);
        __builtin_amdgcn_s_barrier();
        asm volatile("s_waitcnt lgkmcnt(0)" ::: "memory");
        __builtin_amdgcn_sched_barrier(0);
        __builtin_amdgcn_s_setprio(1);
#pragma unroll
        for (int k = 0; k < 2; ++k)
#pragma unroll
            for (int mi = 0; mi < 4; ++mi)
#pragma unroll
                for (int ni = 0; ni < 2; ++ni)
                    acc[4 + mi][2 + ni] = MFMA16(af[mi][k], bf1[ni][k], acc[4 + mi][2 + ni]);
        __builtin_amdgcn_s_setprio(0);
        __builtin_amdgcn_sched_barrier(0);
        __builtin_amdgcn_s_barrier();

        // ===== P3: stage A(t+2) (A regions free after P2); MFMA m1 x n0;
        //           trailing counted gate =====
        if (t + 2 < NT) STAGE_A2(t + 2);
        __builtin_amdgcn_s_barrier();
        __builtin_amdgcn_sched_barrier(0);
        __builtin_amdgcn_s_setprio(1);
#pragma unroll
        for (int k = 0; k < 2; ++k)
#pragma unroll
            for (int mi = 0; mi < 4; ++mi)
#pragma unroll
                for (int ni = 0; ni < 2; ++ni)
                    acc[4 + mi][ni] = MFMA16(af[mi][k], bf0[ni][k], acc[4 + mi][ni]);
        __builtin_amdgcn_s_setprio(0);
        __builtin_amdgcn_sched_barrier(0);
        if (t + 2 < NT)
            asm volatile("s_waitcnt vmcnt(8)" ::: "memory");   // tile t+1's 8 landed
        else
            asm volatile("s_waitcnt vmcnt(0)" ::: "memory");
        __builtin_amdgcn_s_barrier();
    }

    // ---- epilogue: bias+relu, pack bf16x4 over the 4 j-rows, coalesced store ----
    // unit (uint2) index within (e,bm,bn) block: ((wv*8 + m)*4 + n)*64 + lane
    uint2* h1b = H1F + (size_t)((e * nbm + bm) * 4 + bn) * 16384;
#pragma unroll
    for (int m = 0; m < 8; ++m)
#pragma unroll
        for (int n = 0; n < 4; ++n) {
            float v0 = fmaxf(acc[m][n][0] + b1v[n], 0.0f);
            float v1 = fmaxf(acc[m][n][1] + b1v[n], 0.0f);
            float v2 = fmaxf(acc[m][n][2] + b1v[n], 0.0f);
            float v3 = fmaxf(acc[m][n][3] + b1v[n], 0.0f);
            uint2 u;
            u.x = (unsigned int)f2b(v0) | ((unsigned int)f2b(v1) << 16);
            u.y = (unsigned int)f2b(v2) | ((unsigned int)f2b(v3) << 16);
            h1b[((wv * 8 + m) * 4 + n) * 64 + lane] = u;
        }
}

// ---------- pass B: q[b] = relu(sum_e w[b,e]*H1[e,b,:]) . Wh[c[b]] + bh[c[b]] ----------
// One wave per 4 consecutive rows (they share the fragment decode: same wr,m,kg;
// j = 0..3 are the 4 packed bf16 in each uint2). Lane partition: (wc = lane>>4,
// l15 = lane&15); per lane 16 f-slots (bn x n), f = bn*256 + wc*64 + n*16 + l15.
__global__ __launch_bounds__(256)
void k_mixhead(const uint2* __restrict__ H1F, const float* __restrict__ wmix,
               const float* __restrict__ Wh, const float* __restrict__ bh,
               const int* __restrict__ c, float* __restrict__ q,
               int Bc, int row0, int nbm) {
    int lane = threadIdx.x & 63;
    int rg = blockIdx.x * 4 + (threadIdx.x >> 6);
    int rbase = rg * 4;
    if (rbase >= Bc) return;
    int bm = rbase >> 8;
    int lrow = rbase & 255;
    int wr = lrow >> 7, m = (lrow >> 4) & 7, kg = (lrow >> 2) & 3;
    int wc = lane >> 4, l15 = lane & 15;

    float w[4][8];
#pragma unroll
    for (int j = 0; j < 4; ++j)
#pragma unroll
        for (int e = 0; e < 8; ++e)
            w[j][e] = wmix[(size_t)(row0 + rbase + j) * 8 + e];

    float acc[4][16];
#pragma unroll
    for (int j = 0; j < 4; ++j)
#pragma unroll
        for (int s = 0; s < 16; ++s) acc[j][s] = 0.0f;

    int ubase = (((wr * 4 + wc) * 8 + m) * 4) * 64 + kg * 16 + l15;

#pragma unroll 1
    for (int e = 0; e < 8; ++e) {
        size_t eb = (size_t)(e * nbm + bm) * 4;
#pragma unroll
        for (int bn = 0; bn < 4; ++bn) {
            const uint2* blk = H1F + (eb + bn) * 16384;
#pragma unroll
            for (int n = 0; n < 4; ++n) {
                uint2 u = blk[ubase + n * 64];
                float v0 = b2f(u.x & 0xffffu), v1 = b2f(u.x >> 16);
                float v2 = b2f(u.y & 0xffffu), v3 = b2f(u.y >> 16);
                int s = bn * 4 + n;
                acc[0][s] += w[0][e] * v0;
                acc[1][s] += w[1][e] * v1;
                acc[2][s] += w[2][e] * v2;
                acc[3][s] += w[3][e] * v3;
            }
        }
    }

    // head: per row, relu + dot with Wh[c], wave-reduce
#pragma unroll
    for (int j = 0; j < 4; ++j) {
        int grow = row0 + rbase + j;
        int ctx = c[grow];
        const float* whp = Wh + (size_t)ctx * 1024;
        float s = 0.0f;
#pragma unroll
        for (int slot = 0; slot < 16; ++slot) {
            int f = (slot >> 2) * 256 + wc * 64 + (slot & 3) * 16 + l15;
            s += fmaxf(acc[j][slot], 0.0f) * whp[f];
        }
#pragma unroll
        for (int off = 32; off > 0; off >>= 1) s += __shfl_down(s, off);
        if (lane == 0) q[grow] = s + bh[ctx];
    }
}

// ---------- host ----------
extern "C" void kernel_launch(void* const* d_in, const int* in_sizes, int n_in,
                              void* d_out, int out_size, void* d_ws, size_t ws_size,
                              hipStream_t stream) {
    const float* state  = (const float*)d_in[0];
    const float* action = (const float*)d_in[1];
    const int*   c      = (const int*)d_in[2];
    const float* W0     = (const float*)d_in[3];
    const float* b0     = (const float*)d_in[4];
    const float* W1     = (const float*)d_in[5];
    const float* b1     = (const float*)d_in[6];
    const float* Wte    = (const float*)d_in[7];
    const float* Wh     = (const float*)d_in[8];
    const float* bh     = (const float*)d_in[9];
    float* q = (float*)d_out;
    int B = in_sizes[2];

    // workspace layout
    char* p = (char*)d_ws;
    unsigned short* W1T = (unsigned short*)p; p += (size_t)8 * 1024 * 1024 * 2;  // 16 MB
    unsigned short* W0T = (unsigned short*)p; p += (size_t)8 * 1024 * 64 * 2;    // 1 MB
    unsigned short* SA  = (unsigned short*)p; p += (size_t)B * 64 * 2;
    float* wmix         = (float*)p;          p += (size_t)B * 8 * 4;
    size_t fixed = (size_t)(p - (char*)d_ws);

    // per-row chunk cost: H0 16 KB + H1F 16 KB = 32 KB
    int Bc = B;
    while (Bc > 256 && fixed + (size_t)Bc * 32768 > ws_size) Bc >>= 1;

    unsigned short* H0 = (unsigned short*)p; p += (size_t)8 * Bc * 1024 * 2;
    uint2* H1F         = (uint2*)p;          // 8 * Bc * 1024 * 2 bytes

    k_prep_sa<<<(B + 255) / 256, 256, 0, stream>>>(state, action, c, Wte, SA, wmix, B);
    k_prep_w0t<<<(8 * 1024) / 256, 256, 0, stream>>>(W0, W0T);
    k_prep_w1t<<<dim3(16, 16, 8), 256, 0, stream>>>(W1, W1T);

    for (int row0 = 0; row0 < B; row0 += Bc) {
        int nbm = Bc / 256;
        k_layer0<<<dim3(Bc / 128, 8, 8), 256, 0, stream>>>(SA, W0T, b0, H0, Bc, row0);
        k_gemm_h1<<<nbm * 32, 512, 0, stream>>>(H0, W1T, b1, H1F, Bc, nbm);
        k_mixhead<<<Bc / 16, 256, 0, stream>>>(H1F, wmix, Wh, bh, c, q, Bc, row0, nbm);
    }
}

// Round 10
// 236.469 us; speedup vs baseline: 1.1912x; 1.0641x over previous
//
#include <hip/hip_runtime.h>
#include <hip/hip_bf16.h>
#include <stdint.h>

// ---------- types ----------
typedef __attribute__((ext_vector_type(8))) __bf16 bf16x8;
typedef __attribute__((ext_vector_type(4))) float f32x4;

__device__ __forceinline__ unsigned short f2b(float f) {
    return __builtin_bit_cast(unsigned short, __float2bfloat16(f));
}
__device__ __forceinline__ float b2f(unsigned int u) {   // low 16 bits = bf16
    return __builtin_bit_cast(float, u << 16);
}

// async global -> LDS, 16B per lane (wave-uniform base + lane*16 dest order)
__device__ __forceinline__ void gload_lds16(const void* g, void* l) {
    __builtin_amdgcn_global_load_lds(
        (__attribute__((address_space(1))) void*)(uintptr_t)g,
        (__attribute__((address_space(3))) void*)l,
        16, 0, 0);
}

#define MFMA16(a, b, c) __builtin_amdgcn_mfma_f32_16x16x32_bf16((a), (b), (c), 0, 0, 0)

// ---------- constants ----------
// B=8192, S=39, A=4, D_IN=43 (pad 64), F=1024, E=8, C=10

// ---------- prep: SA pack + mixture weights ----------
__global__ void k_prep_sa(const float* __restrict__ state, const float* __restrict__ action,
                          const int* __restrict__ c, const float* __restrict__ Wte,
                          unsigned short* __restrict__ SA, float* __restrict__ wmix, int B) {
    int b = blockIdx.x * 256 + threadIdx.x;
    if (b >= B) return;
    unsigned short* row = SA + (size_t)b * 64;
#pragma unroll
    for (int i = 0; i < 39; ++i) row[i] = f2b(state[(size_t)b * 39 + i]);
#pragma unroll
    for (int i = 0; i < 4; ++i) row[39 + i] = f2b(action[(size_t)b * 4 + i]);
#pragma unroll
    for (int i = 43; i < 64; ++i) row[i] = 0;
    int ctx = c[b];
#pragma unroll
    for (int e = 0; e < 8; ++e) wmix[(size_t)b * 8 + e] = Wte[e * 10 + ctx];
}

// ---------- prep: W0 [E,43,1024] f32 -> W0T [E,1024,64] bf16 ----------
__global__ void k_prep_w0t(const float* __restrict__ W0, unsigned short* __restrict__ W0T) {
    int idx = blockIdx.x * 256 + threadIdx.x;   // e*1024 + f
    int e = idx >> 10, f = idx & 1023;
    unsigned short* dst = W0T + (size_t)idx * 64;
#pragma unroll 1
    for (int k = 0; k < 43; ++k) dst[k] = f2b(W0[((size_t)e * 43 + k) * 1024 + f]);
#pragma unroll
    for (int k = 43; k < 64; ++k) dst[k] = 0;
}

// ---------- prep: W1 [E,1024,1024] f32 -> W1T [E,1024(n),1024(k)] bf16 ----------
__global__ void k_prep_w1t(const float* __restrict__ W1, unsigned short* __restrict__ W1T) {
    __shared__ float t[64][65];
    int k0 = blockIdx.x * 64, n0 = blockIdx.y * 64, e = blockIdx.z;
    int tid = threadIdx.x;
    int cl = tid & 63, rg = tid >> 6;
    const float* src = W1 + ((size_t)e * 1024 + k0) * 1024 + n0;
#pragma unroll
    for (int i = 0; i < 16; ++i) {
        int kr = rg * 16 + i;
        t[kr][cl] = src[(size_t)kr * 1024 + cl];
    }
    __syncthreads();
    int nl = tid >> 2, kg = tid & 3;
    unsigned short* dst = W1T + ((size_t)e * 1024 + n0 + nl) * 1024 + k0 + kg * 16;
#pragma unroll
    for (int j = 0; j < 16; ++j) dst[j] = f2b(t[kg * 16 + j][nl]);
}

// ---------- layer 0: H0[e] = relu(SA @ W0T[e]^T + b0[e]), bf16 out (full B) ----------
__global__ __launch_bounds__(256, 2)
void k_layer0(const unsigned short* __restrict__ SA,
              const unsigned short* __restrict__ W0T,
              const float* __restrict__ b0,
              unsigned short* __restrict__ H0,
              int Btot) {
    __shared__ unsigned short As[128 * 64];
    __shared__ unsigned short Bs[128 * 64];
    int bm = blockIdx.x, bn = blockIdx.y, e = blockIdx.z;
    int tid = threadIdx.x, lane = tid & 63;
    int wv = tid >> 6, wr = wv >> 1, wc = wv & 1;
    int l15 = lane & 15, kg = lane >> 4;

    const char* Ag = (const char*)(SA + (size_t)(bm * 128) * 64);
    const char* Bg = (const char*)(W0T + ((size_t)e * 1024 + bn * 128) * 64);
#pragma unroll
    for (int it = 0; it < 4; ++it) {
        int off = tid * 16 + it * 4096;
        gload_lds16(Ag + off, (char*)As + off);
        gload_lds16(Bg + off, (char*)Bs + off);
    }
    __syncthreads();

    f32x4 acc[4][4];
#pragma unroll
    for (int mi = 0; mi < 4; ++mi)
#pragma unroll
        for (int ni = 0; ni < 4; ++ni) acc[mi][ni] = (f32x4)0.0f;

#pragma unroll
    for (int ks = 0; ks < 2; ++ks) {
        bf16x8 af[4], bv[4];
#pragma unroll
        for (int mi = 0; mi < 4; ++mi)
            af[mi] = *(const bf16x8*)&As[(wr * 64 + mi * 16 + l15) * 64 + ks * 32 + kg * 8];
#pragma unroll
        for (int ni = 0; ni < 4; ++ni)
            bv[ni] = *(const bf16x8*)&Bs[(wc * 64 + ni * 16 + l15) * 64 + ks * 32 + kg * 8];
#pragma unroll
        for (int mi = 0; mi < 4; ++mi)
#pragma unroll
            for (int ni = 0; ni < 4; ++ni)
                acc[mi][ni] = MFMA16(af[mi], bv[ni], acc[mi][ni]);
    }

    float b0v[4];
#pragma unroll
    for (int ni = 0; ni < 4; ++ni)
        b0v[ni] = b0[e * 1024 + bn * 128 + wc * 64 + ni * 16 + l15];
#pragma unroll
    for (int mi = 0; mi < 4; ++mi)
#pragma unroll
        for (int ni = 0; ni < 4; ++ni)
#pragma unroll
            for (int j = 0; j < 4; ++j) {
                int rloc = bm * 128 + wr * 64 + mi * 16 + kg * 4 + j;
                int col = bn * 128 + wc * 64 + ni * 16 + l15;
                float h = fmaxf(acc[mi][ni][j] + b0v[ni], 0.0f);
                H0[((size_t)e * Btot + rloc) * 1024 + col] = f2b(h);
            }
}

// ---------- pass A: H1[e] = relu(H0[e] @ W1T[e]^T + b1[e]), fragment-layout bf16 ----------
// 256x256 block, 8 waves (2M x 4N) of 128x64, BK=64, double-buffered (128 KB LDS).
// READ-AHEAD schedule (fixes R9's per-phase lgkm stall): ds_reads issued in phase k
// feed phase k+1's MFMA. Quadrants: Q0=(m0,n0) Q1=(m0,n1) Q2=(m1,n0) Q3=(m1,n1).
//   P0: issue B(n1)[4];       lgkm(4)  -> Q0 frags ready; MFMA Q0; barrier
//   P1: issue A(m1)[8];       lgkm(8)  -> B(n1) ready;    MFMA Q1; barrier
//   P2: stage B(t+2);         lgkm(0)  -> A(m1) ready;    MFMA Q2; vmcnt(4); barrier
//   P3: issue next-tile Q0 frags[12] (buf t+1, certified by P2's vmcnt) + stage A(t+2);
//       NO wait (Q3 from regs);                           MFMA Q3; barrier
// Write-after-read: B-region of buf[t] last read-complete at P1 (certified by P1
// barrier) -> stage B(t+2) at P2 safe; A-region at P2 -> stage A(t+2) at P3 safe.
// FIFO at P2-end: [B(t+1)4 A(t+1)4 B(t+2)4] -> vmcnt(4) certifies tile t+1 (3-phase lead).
__global__ __launch_bounds__(512, 2)
void k_gemm_h1(const unsigned short* __restrict__ H0,   // [E,Btot,1024]
               const unsigned short* __restrict__ W1T,  // [E,1024(n),1024(k)]
               const float* __restrict__ b1,            // [E,1024]
               uint2* __restrict__ H1F,                 // fragment layout (chunk-local)
               int Btot, int row0, int nbm) {
    __shared__ unsigned short SH[65536];   // 128 KB: A bytes [0,65536), B [65536,131072)

    // XCD-coherent decode (xcd = wg%8): 4 bn-siblings of one (e,bm) share one L2.
    int wg = blockIdx.x;
    int c8 = wg & 7, r = wg >> 3;
    int bn = r & 3, pg = r >> 2;
    int pair = c8 + 8 * pg;                // pair = e*nbm + bm, npair = 8*nbm (%8==0)
    int e = pair / nbm, bm = pair - e * nbm;

    int tid = threadIdx.x, lane = tid & 63;
    int wv = tid >> 6;
    int wr = wv >> 2, wc = wv & 3;         // 2M x 4N wave grid
    int l15 = lane & 15, kg = lane >> 4;
    int k0s = (kg * 16) ^ ((l15 & 7) << 4);
    int k1s = (64 + kg * 16) ^ ((l15 & 7) << 4);

    // staging per-thread offsets
    int flat = tid * 16;
    int srow = flat >> 7;                          // 0..63
    int scol = (flat & 127) ^ ((srow & 7) << 4);   // inverse-swizzled source col

    const char* h0e = (const char*)H0 + ((size_t)e * Btot + row0 + (size_t)bm * 256) * 2048;
    const char* w1e = (const char*)W1T + ((size_t)e * 1024 + (size_t)bn * 256) * 2048;
    char* Asb = (char*)SH;
    char* Bsb = (char*)SH + 65536;

    // fragment read offsets (rows local to the wave's half; row&7 == l15&7)
    int aRow[8], bRow[4];
#pragma unroll
    for (int m = 0; m < 8; ++m) aRow[m] = (((m >> 2) * 64) + (m & 3) * 16 + l15) * 128;
#pragma unroll
    for (int n = 0; n < 4; ++n) bRow[n] = ((wc & 1) * 64 + n * 16 + l15) * 128;

    // bias: load + retire BEFORE the pipeline (keeps vmcnt FIFO clean)
    float b1v[4];
#pragma unroll
    for (int n = 0; n < 4; ++n)
        b1v[n] = b1[e * 1024 + bn * 256 + wc * 64 + n * 16 + l15];
    asm volatile("s_waitcnt vmcnt(0)" ::: "memory");

    auto STAGE_B2 = [&](int tt) {   // full B K-tile (4 gloads)
        int k0b = tt << 7;
        char* dstb = Bsb + (tt & 1) * 32768;
        const char* s0 = w1e + k0b;
        gload_lds16(s0 + (size_t)srow * 2048 + scol, dstb + flat);
        gload_lds16(s0 + (size_t)(srow + 64) * 2048 + scol, dstb + flat + 8192);
        const char* s1 = w1e + (size_t)128 * 2048 + k0b;
        gload_lds16(s1 + (size_t)srow * 2048 + scol, dstb + 16384 + flat);
        gload_lds16(s1 + (size_t)(srow + 64) * 2048 + scol, dstb + 16384 + flat + 8192);
    };
    auto STAGE_A2 = [&](int tt) {   // full A K-tile (4 gloads)
        int k0b = tt << 7;
        char* dsta = Asb + (tt & 1) * 32768;
        const char* s0 = h0e + k0b;
        gload_lds16(s0 + (size_t)srow * 2048 + scol, dsta + flat);
        gload_lds16(s0 + (size_t)(srow + 64) * 2048 + scol, dsta + flat + 8192);
        const char* s1 = h0e + (size_t)128 * 2048 + k0b;
        gload_lds16(s1 + (size_t)srow * 2048 + scol, dsta + 16384 + flat);
        gload_lds16(s1 + (size_t)(srow + 64) * 2048 + scol, dsta + 16384 + flat + 8192);
    };

    const int NT = 16;   // K = 1024 / BK 64

    // prologue: stage tiles 0,1 (FIFO [B0 A0 B1 A1]); vmcnt(8) drains tile 0
    STAGE_B2(0); STAGE_A2(0);
    STAGE_B2(1); STAGE_A2(1);
    asm volatile("s_waitcnt vmcnt(8)" ::: "memory");
    __builtin_amdgcn_s_barrier();

    f32x4 acc[8][4];
#pragma unroll
    for (int m = 0; m < 8; ++m)
#pragma unroll
        for (int n = 0; n < 4; ++n) acc[m][n] = (f32x4)0.0f;

    // loop-carried fragments: af0 = A(m0), bf0 = B(n0) of CURRENT tile (read in prev P3)
    bf16x8 af0[4][2], af1[4][2], bf0[2][2], bf1[2][2];

    // pre-issue tile-0 Q0 fragments (12 ds_reads, awaited at P0's lgkm(4))
    {
        const char* Ab = Asb + (0 * 2 + wr) * 16384;
        const char* Bb = Bsb + (0 * 2 + (wc >> 1)) * 16384;
#pragma unroll
        for (int mi = 0; mi < 4; ++mi) {
            af0[mi][0] = *(const bf16x8*)(Ab + aRow[mi] + k0s);
            af0[mi][1] = *(const bf16x8*)(Ab + aRow[mi] + k1s);
        }
#pragma unroll
        for (int ni = 0; ni < 2; ++ni) {
            bf0[ni][0] = *(const bf16x8*)(Bb + bRow[ni] + k0s);
            bf0[ni][1] = *(const bf16x8*)(Bb + bRow[ni] + k1s);
        }
    }

#pragma unroll 1
    for (int t = 0; t < NT; ++t) {
        int buf = t & 1, nb = buf ^ 1;
        const char* Ab = Asb + (buf * 2 + wr) * 16384;
        const char* Bb = Bsb + (buf * 2 + (wc >> 1)) * 16384;
        const char* AbN = Asb + (nb * 2 + wr) * 16384;
        const char* BbN = Bsb + (nb * 2 + (wc >> 1)) * 16384;

        // ===== P0: issue B(n1)[4]; lgkm(4) -> Q0 frags ready; MFMA Q0 =====
#pragma unroll
        for (int ni = 0; ni < 2; ++ni) {
            bf1[ni][0] = *(const bf16x8*)(Bb + bRow[2 + ni] + k0s);
            bf1[ni][1] = *(const bf16x8*)(Bb + bRow[2 + ni] + k1s);
        }
        asm volatile("s_waitcnt lgkmcnt(4)" ::: "memory");
        __builtin_amdgcn_sched_barrier(0);
        __builtin_amdgcn_s_setprio(1);
#pragma unroll
        for (int k = 0; k < 2; ++k)
#pragma unroll
            for (int mi = 0; mi < 4; ++mi)
#pragma unroll
                for (int ni = 0; ni < 2; ++ni)
                    acc[mi][ni] = MFMA16(af0[mi][k], bf0[ni][k], acc[mi][ni]);
        __builtin_amdgcn_s_setprio(0);
        __builtin_amdgcn_sched_barrier(0);
        __builtin_amdgcn_s_barrier();

        // ===== P1: issue A(m1)[8]; lgkm(8) -> B(n1) ready; MFMA Q1 =====
#pragma unroll
        for (int mi = 0; mi < 4; ++mi) {
            af1[mi][0] = *(const bf16x8*)(Ab + aRow[4 + mi] + k0s);
            af1[mi][1] = *(const bf16x8*)(Ab + aRow[4 + mi] + k1s);
        }
        asm volatile("s_waitcnt lgkmcnt(8)" ::: "memory");
        __builtin_amdgcn_sched_barrier(0);
        __builtin_amdgcn_s_setprio(1);
#pragma unroll
        for (int k = 0; k < 2; ++k)
#pragma unroll
            for (int mi = 0; mi < 4; ++mi)
#pragma unroll
                for (int ni = 0; ni < 2; ++ni)
                    acc[mi][2 + ni] = MFMA16(af0[mi][k], bf1[ni][k], acc[mi][2 + ni]);
        __builtin_amdgcn_s_setprio(0);
        __builtin_amdgcn_sched_barrier(0);
        __builtin_amdgcn_s_barrier();

        // ===== P2: stage B(t+2); lgkm(0) -> A(m1) ready; MFMA Q2; vmcnt gate =====
        if (t + 2 < NT) STAGE_B2(t + 2);
        asm volatile("s_waitcnt lgkmcnt(0)" ::: "memory");
        __builtin_amdgcn_sched_barrier(0);
        __builtin_amdgcn_s_setprio(1);
#pragma unroll
        for (int k = 0; k < 2; ++k)
#pragma unroll
            for (int mi = 0; mi < 4; ++mi)
#pragma unroll
                for (int ni = 0; ni < 2; ++ni)
                    acc[4 + mi][ni] = MFMA16(af1[mi][k], bf0[ni][k], acc[4 + mi][ni]);
        __builtin_amdgcn_s_setprio(0);
        __builtin_amdgcn_sched_barrier(0);
        if (t + 2 < NT)
            asm volatile("s_waitcnt vmcnt(4)" ::: "memory");   // tile t+1 landed
        else
            asm volatile("s_waitcnt vmcnt(0)" ::: "memory");
        __builtin_amdgcn_s_barrier();

        // ===== P3: issue next-tile Q0 frags [12] + stage A(t+2); MFMA Q3 (regs) =====
        if (t + 1 < NT) {
#pragma unroll
            for (int mi = 0; mi < 4; ++mi) {
                af0[mi][0] = *(const bf16x8*)(AbN + aRow[mi] + k0s);
                af0[mi][1] = *(const bf16x8*)(AbN + aRow[mi] + k1s);
            }
#pragma unroll
            for (int ni = 0; ni < 2; ++ni) {
                bf0[ni][0] = *(const bf16x8*)(BbN + bRow[ni] + k0s);
                bf0[ni][1] = *(const bf16x8*)(BbN + bRow[ni] + k1s);
            }
        }
        if (t + 2 < NT) STAGE_A2(t + 2);
        __builtin_amdgcn_sched_barrier(0);
        __builtin_amdgcn_s_setprio(1);
#pragma unroll
        for (int k = 0; k < 2; ++k)
#pragma unroll
            for (int mi = 0; mi < 4; ++mi)
#pragma unroll
                for (int ni = 0; ni < 2; ++ni)
                    acc[4 + mi][2 + ni] = MFMA16(af1[mi][k], bf1[ni][k], acc[4 + mi][2 + ni]);
        __builtin_amdgcn_s_setprio(0);
        __builtin_amdgcn_sched_barrier(0);
        __builtin_amdgcn_s_barrier();
    }

    // ---- epilogue: bias+relu, pack bf16x4 over the 4 j-rows, coalesced store ----
    uint2* h1b = H1F + (size_t)((e * nbm + bm) * 4 + bn) * 16384;
#pragma unroll
    for (int m = 0; m < 8; ++m)
#pragma unroll
        for (int n = 0; n < 4; ++n) {
            float v0 = fmaxf(acc[m][n][0] + b1v[n], 0.0f);
            float v1 = fmaxf(acc[m][n][1] + b1v[n], 0.0f);
            float v2 = fmaxf(acc[m][n][2] + b1v[n], 0.0f);
            float v3 = fmaxf(acc[m][n][3] + b1v[n], 0.0f);
            uint2 u;
            u.x = (unsigned int)f2b(v0) | ((unsigned int)f2b(v1) << 16);
            u.y = (unsigned int)f2b(v2) | ((unsigned int)f2b(v3) << 16);
            h1b[((wv * 8 + m) * 4 + n) * 64 + lane] = u;
        }
}

// ---------- pass B: q[b] = relu(sum_e w[b,e]*H1[e,b,:]) . Wh[c[b]] + bh[c[b]] ----------
__global__ __launch_bounds__(256)
void k_mixhead(const uint2* __restrict__ H1F, const float* __restrict__ wmix,
               const float* __restrict__ Wh, const float* __restrict__ bh,
               const int* __restrict__ c, float* __restrict__ q,
               int Bc, int row0, int nbm) {
    int lane = threadIdx.x & 63;
    int rg = blockIdx.x * 4 + (threadIdx.x >> 6);
    int rbase = rg * 4;
    if (rbase >= Bc) return;
    int bm = rbase >> 8;
    int lrow = rbase & 255;
    int wr = lrow >> 7, m = (lrow >> 4) & 7, kg = (lrow >> 2) & 3;
    int wc = lane >> 4, l15 = lane & 15;

    float w[4][8];
#pragma unroll
    for (int j = 0; j < 4; ++j)
#pragma unroll
        for (int e = 0; e < 8; ++e)
            w[j][e] = wmix[(size_t)(row0 + rbase + j) * 8 + e];

    float acc[4][16];
#pragma unroll
    for (int j = 0; j < 4; ++j)
#pragma unroll
        for (int s = 0; s < 16; ++s) acc[j][s] = 0.0f;

    int ubase = (((wr * 4 + wc) * 8 + m) * 4) * 64 + kg * 16 + l15;

#pragma unroll 1
    for (int e = 0; e < 8; ++e) {
        size_t eb = (size_t)(e * nbm + bm) * 4;
#pragma unroll
        for (int bn = 0; bn < 4; ++bn) {
            const uint2* blk = H1F + (eb + bn) * 16384;
#pragma unroll
            for (int n = 0; n < 4; ++n) {
                uint2 u = blk[ubase + n * 64];
                float v0 = b2f(u.x & 0xffffu), v1 = b2f(u.x >> 16);
                float v2 = b2f(u.y & 0xffffu), v3 = b2f(u.y >> 16);
                int s = bn * 4 + n;
                acc[0][s] += w[0][e] * v0;
                acc[1][s] += w[1][e] * v1;
                acc[2][s] += w[2][e] * v2;
                acc[3][s] += w[3][e] * v3;
            }
        }
    }

#pragma unroll
    for (int j = 0; j < 4; ++j) {
        int grow = row0 + rbase + j;
        int ctx = c[grow];
        const float* whp = Wh + (size_t)ctx * 1024;
        float s = 0.0f;
#pragma unroll
        for (int slot = 0; slot < 16; ++slot) {
            int f = (slot >> 2) * 256 + wc * 64 + (slot & 3) * 16 + l15;
            s += fmaxf(acc[j][slot], 0.0f) * whp[f];
        }
#pragma unroll
        for (int off = 32; off > 0; off >>= 1) s += __shfl_down(s, off);
        if (lane == 0) q[grow] = s + bh[ctx];
    }
}

// ---------- host ----------
extern "C" void kernel_launch(void* const* d_in, const int* in_sizes, int n_in,
                              void* d_out, int out_size, void* d_ws, size_t ws_size,
                              hipStream_t stream) {
    const float* state  = (const float*)d_in[0];
    const float* action = (const float*)d_in[1];
    const int*   c      = (const int*)d_in[2];
    const float* W0     = (const float*)d_in[3];
    const float* b0     = (const float*)d_in[4];
    const float* W1     = (const float*)d_in[5];
    const float* b1     = (const float*)d_in[6];
    const float* Wte    = (const float*)d_in[7];
    const float* Wh     = (const float*)d_in[8];
    const float* bh     = (const float*)d_in[9];
    float* q = (float*)d_out;
    int B = in_sizes[2];

    // workspace layout
    char* p = (char*)d_ws;
    unsigned short* W1T = (unsigned short*)p; p += (size_t)8 * 1024 * 1024 * 2;  // 16 MB
    unsigned short* W0T = (unsigned short*)p; p += (size_t)8 * 1024 * 64 * 2;    // 1 MB
    unsigned short* SA  = (unsigned short*)p; p += (size_t)B * 64 * 2;
    float* wmix         = (float*)p;          p += (size_t)B * 8 * 4;
    size_t fixed = (size_t)(p - (char*)d_ws);

    // H0 is allocated FULL-B (layer0 launched once); only H1F is chunked.
    size_t h0sz = (size_t)8 * B * 1024 * 2;
    unsigned short* H0 = (unsigned short*)p; p += h0sz;

    int Bc = B;   // largest H1F chunk that fits
    while (Bc > 256 && fixed + h0sz + (size_t)8 * Bc * 1024 * 2 > ws_size) Bc >>= 1;
    uint2* H1F = (uint2*)p;

    k_prep_sa<<<(B + 255) / 256, 256, 0, stream>>>(state, action, c, Wte, SA, wmix, B);
    k_prep_w0t<<<(8 * 1024) / 256, 256, 0, stream>>>(W0, W0T);
    k_prep_w1t<<<dim3(16, 16, 8), 256, 0, stream>>>(W1, W1T);
    k_layer0<<<dim3(B / 128, 8, 8), 256, 0, stream>>>(SA, W0T, b0, H0, B);

    for (int row0 = 0; row0 < B; row0 += Bc) {
        int nbm = Bc / 256;
        k_gemm_h1<<<nbm * 32, 512, 0, stream>>>(H0, W1T, b1, H1F, B, row0, nbm);
        k_mixhead<<<Bc / 16, 256, 0, stream>>>(H1F, wmix, Wh, bh, c, q, Bc, row0, nbm);
    }
}